// Round 9
// baseline (393.369 us; speedup 1.0000x reference)
//
#include <hip/hip_runtime.h>
#include <hip/hip_bf16.h>
#include <math.h>

#define B_ 32
#define N_ 576
#define C_ 1024
#define INNER_ 256
#define H_ 4
#define HD_ 64
#define M_ (B_*N_)           // 18432
#define ALPHA_ 5.0f
#define EPS_ 1e-5f

typedef __attribute__((ext_vector_type(8))) short bf16x8;
typedef __attribute__((ext_vector_type(4))) float f32x4;
typedef __attribute__((ext_vector_type(4))) unsigned int u32x4;
typedef unsigned short u16;

__device__ inline u16 bfbits(float x) {
    union { __hip_bfloat16 h; u16 u; } c; c.h = __float2bfloat16(x); return c.u;
}
__device__ inline float bf2f(u16 u) {
    union { unsigned u32; float f; } c; c.u32 = ((unsigned)u) << 16; return c.f;
}
__device__ inline unsigned pack2bf(float a, float b) {
    return (unsigned)bfbits(a) | ((unsigned)bfbits(b) << 16);
}

// Async global->LDS, 16B per lane. LDS dest: wave-uniform base + lane*16.
__device__ __forceinline__ void gld16(void* lds, const void* g) {
    __builtin_amdgcn_global_load_lds(
        (const __attribute__((address_space(1))) unsigned int*)g,
        (__attribute__((address_space(3))) unsigned int*)lds, 16, 0, 0);
}

// XCD row-clustering swizzle (bijective when GY % 8 == 0).
template<int GX, int GY>
__device__ inline void xcd_remap(int& col, int& row) {
    int f = blockIdx.y * GX + blockIdx.x;
    int xcd = f & 7;
    int slot = f >> 3;
    col = slot % GX;
    row = xcd * (GY >> 3) + slot / GX;
}

// ---------------------------------------------------------------------------
// Fused LayerNorm for both tensors; query pass (blockIdx.y==0) also emits the
// raw input as bf16 (Xq) for the gate GEMM.
// ---------------------------------------------------------------------------
__global__ void ln_fused2_kernel(const float* __restrict__ Xq, const float* __restrict__ Xs,
                                 const float* __restrict__ wq, const float* __restrict__ bq,
                                 const float* __restrict__ ws, const float* __restrict__ bs,
                                 u16* __restrict__ outq, u16* __restrict__ outs,
                                 u16* __restrict__ outraw) {
    const float* X; const float* w; const float* b; u16* o;
    bool raw = (blockIdx.y == 0);
    if (raw) { X = Xq; w = wq; b = bq; o = outq; }
    else     { X = Xs; w = ws; b = bs; o = outs; }
    int row = blockIdx.x * 4 + (threadIdx.x >> 6);
    int lane = threadIdx.x & 63;
    const float* xp = X + (size_t)row * C_;
    float4 v[4];
    #pragma unroll
    for (int j = 0; j < 4; ++j) v[j] = *(const float4*)(xp + lane*4 + j*256);
    float s = 0.f, s2 = 0.f;
    #pragma unroll
    for (int j = 0; j < 4; ++j) {
        s  += v[j].x + v[j].y + v[j].z + v[j].w;
        s2 += v[j].x*v[j].x + v[j].y*v[j].y + v[j].z*v[j].z + v[j].w*v[j].w;
    }
    #pragma unroll
    for (int m = 32; m; m >>= 1) {
        s  += __shfl_xor(s,  m, 64);
        s2 += __shfl_xor(s2, m, 64);
    }
    float mean = s * (1.f/C_);
    float rs = rsqrtf(s2 * (1.f/C_) - mean*mean + EPS_);
    #pragma unroll
    for (int j = 0; j < 4; ++j) {
        int k = lane*4 + j*256;
        float4 wv = *(const float4*)(w + k);
        float4 bv = *(const float4*)(b + k);
        ushort4 ov;
        ov.x = bfbits((v[j].x - mean)*rs*wv.x + bv.x);
        ov.y = bfbits((v[j].y - mean)*rs*wv.y + bv.y);
        ov.z = bfbits((v[j].z - mean)*rs*wv.z + bv.z);
        ov.w = bfbits((v[j].w - mean)*rs*wv.w + bv.w);
        *(ushort4*)(o + (size_t)row*C_ + k) = ov;
        if (raw) {
            ushort4 r4;
            r4.x = bfbits(v[j].x); r4.y = bfbits(v[j].y);
            r4.z = bfbits(v[j].z); r4.w = bfbits(v[j].w);
            *(ushort4*)(outraw + (size_t)row*C_ + k) = r4;
        }
    }
}

// ---------------------------------------------------------------------------
// Weight conversions: Wall[1792][1024] = Wq|Wk|Wv|Wg rows, Wo_b separate.
// ---------------------------------------------------------------------------
__global__ void cvt_weights_kernel(const float* __restrict__ Wq, const float* __restrict__ Wk,
                                   const float* __restrict__ Wv, const float* __restrict__ Wo,
                                   const float* __restrict__ Wg,
                                   u16* __restrict__ Wall, u16* __restrict__ Wo_b) {
    int g = blockIdx.x * 256 + threadIdx.x;
    const float* src; u16* dst; size_t off;
    if (g < 32768)       { src = Wq; dst = Wall;          off = (size_t)g*8; }
    else if (g < 65536)  { src = Wk; dst = Wall + 262144; off = (size_t)(g-32768)*8; }
    else if (g < 98304)  { src = Wv; dst = Wall + 524288; off = (size_t)(g-65536)*8; }
    else if (g < 131072) { src = Wo; dst = Wo_b;          off = (size_t)(g-98304)*8; }
    else                 { src = Wg; dst = Wall + 786432; off = (size_t)(g-131072)*8; }
    float4 a0 = *(const float4*)(src + off);
    float4 a1 = *(const float4*)(src + off + 4);
    union { u16 s[8]; u32x4 v; } o;
    o.s[0] = bfbits(a0.x); o.s[1] = bfbits(a0.y); o.s[2] = bfbits(a0.z); o.s[3] = bfbits(a0.w);
    o.s[4] = bfbits(a1.x); o.s[5] = bfbits(a1.y); o.s[6] = bfbits(a1.z); o.s[7] = bfbits(a1.w);
    *(u32x4*)(dst + off) = o.v;
}

// ---------------------------------------------------------------------------
// Mega GEMM: 256(M) x 128(N) tile, BK=32, 8 waves (4M x 2N), per-wave 64x64.
// Single-buffered gld_lds staging (24 KB LDS). Output columns:
// bc 0-1 = Q proj, bc 2-5 = KV proj, bc 6-13 = gate (sigmoid, bf16).
// ---------------------------------------------------------------------------
__global__ __launch_bounds__(512, 4)
void mega_gemm_kernel(const u16* __restrict__ Aq, const u16* __restrict__ As,
                      const u16* __restrict__ Xq, const u16* __restrict__ Wall,
                      const float* __restrict__ bq, const float* __restrict__ bk,
                      const float* __restrict__ bv, const float* __restrict__ bg,
                      u16* __restrict__ Qbf, u16* __restrict__ KVbf,
                      u16* __restrict__ Gbf) {
    __shared__ u16 Asm[256*32];   // 16 KB
    __shared__ u16 Bsm[128*32];   //  8 KB
    int tid = threadIdx.x;
    int lane = tid & 63, wid = tid >> 6;
    int wm = (wid >> 1) * 64, wn = (wid & 1) * 64;
    int bc, br;
    xcd_remap<14, 72>(bc, br);
    int row0 = br * 256;
    int wrow0 = bc * 128;
    const u16* A = (bc < 2) ? Aq : (bc < 6) ? As : Xq;

    f32x4 acc[4][4] = {};

    int rA = tid >> 2;              // 0..127
    int c8 = (tid & 3) * 8;         // 0,8,16,24

    for (int k0 = 0; k0 < C_; k0 += 32) {
        gld16(&Asm[(size_t)tid*8],         A + (size_t)(row0 + rA)*C_ + k0 + c8);
        gld16(&Asm[(size_t)(512+tid)*8],   A + (size_t)(row0 + 128 + rA)*C_ + k0 + c8);
        gld16(&Bsm[(size_t)tid*8],         Wall + (size_t)(wrow0 + rA)*C_ + k0 + c8);
        __syncthreads();
        bf16x8 af[4], bfv[4];
        #pragma unroll
        for (int i = 0; i < 4; ++i)
            af[i] = *(const bf16x8*)&Asm[(wm + i*16 + (lane & 15))*32 + (lane >> 4)*8];
        #pragma unroll
        for (int j = 0; j < 4; ++j)
            bfv[j] = *(const bf16x8*)&Bsm[(wn + j*16 + (lane & 15))*32 + (lane >> 4)*8];
        #pragma unroll
        for (int i = 0; i < 4; ++i)
            #pragma unroll
            for (int j = 0; j < 4; ++j)
                acc[i][j] = __builtin_amdgcn_mfma_f32_16x16x32_bf16(
                    af[i], bfv[j], acc[i][j], 0, 0, 0);
        __syncthreads();
    }

    // epilogue: route by global output column
    #pragma unroll
    for (int j = 0; j < 4; ++j) {
        int lc = wn + j*16 + (lane & 15);       // 0..127 within tile
        int obc = wrow0 + lc;                   // global output column 0..1791
        float bb;
        if (obc < 256)      bb = bq[obc];
        else if (obc < 512) bb = bk[obc - 256];
        else if (obc < 768) bb = bv[obc - 512];
        else                bb = bg[obc - 768];
        #pragma unroll
        for (int i = 0; i < 4; ++i) {
            #pragma unroll
            for (int r = 0; r < 4; ++r) {
                int row = row0 + wm + i*16 + (lane >> 4)*4 + r;
                float v = acc[i][j][r] + bb;
                if (obc < 256)
                    Qbf[(size_t)row*256 + obc] = bfbits(v);
                else if (obc < 768)
                    KVbf[(size_t)row*512 + (obc - 256)] = bfbits(v);
                else
                    Gbf[(size_t)row*1024 + (obc - 768)] =
                        bfbits(1.f / (1.f + expf(-v)));
            }
        }
    }
}

// ---------------------------------------------------------------------------
// final_lite: out = query + gate * (ctx@Wo^T + bo). K=256, 128x128 tile,
// reg-staged padded LDS (r6-validated structure).
// ---------------------------------------------------------------------------
__global__ __launch_bounds__(256, 2)
void final_lite_kernel(const float* __restrict__ query, const u16* __restrict__ Gbf,
                       const u16* __restrict__ ctxb, const u16* __restrict__ Wo_b,
                       const float* __restrict__ bo, float* __restrict__ out) {
    __shared__ u16 Asm[128][72];
    __shared__ u16 Bsm[128][72];
    int tid = threadIdx.x;
    int lane = tid & 63, wid = tid >> 6;
    int wm = (wid >> 1) * 64, wn = (wid & 1) * 64;
    int bc, br;
    xcd_remap<8, 144>(bc, br);
    int row0 = br * 128, col0 = bc * 128;
    f32x4 acc[4][4] = {};
    for (int k0 = 0; k0 < INNER_; k0 += 64) {
        #pragma unroll
        for (int i = 0; i < 4; ++i) {
            int s = tid + i*256;
            int r = s >> 3, cg = (s & 7) * 8;
            *(u32x4*)&Asm[r][cg] = *(const u32x4*)(ctxb + (size_t)(row0 + r)*INNER_ + k0 + cg);
            *(u32x4*)&Bsm[r][cg] = *(const u32x4*)(Wo_b + (size_t)(col0 + r)*INNER_ + k0 + cg);
        }
        __syncthreads();
        #pragma unroll
        for (int ks = 0; ks < 64; ks += 32) {
            bf16x8 af[4], bfr[4];
            #pragma unroll
            for (int i = 0; i < 4; ++i)
                af[i] = *(const bf16x8*)&Asm[wm + i*16 + (lane & 15)][ks + (lane >> 4)*8];
            #pragma unroll
            for (int j = 0; j < 4; ++j)
                bfr[j] = *(const bf16x8*)&Bsm[wn + j*16 + (lane & 15)][ks + (lane >> 4)*8];
            #pragma unroll
            for (int i = 0; i < 4; ++i)
                #pragma unroll
                for (int j = 0; j < 4; ++j)
                    acc[i][j] = __builtin_amdgcn_mfma_f32_16x16x32_bf16(
                        af[i], bfr[j], acc[i][j], 0, 0, 0);
        }
        __syncthreads();
    }
    #pragma unroll
    for (int i = 0; i < 4; ++i) {
        #pragma unroll
        for (int j = 0; j < 4; ++j) {
            int col = col0 + wn + j*16 + (lane & 15);
            float bov = bo[col];
            #pragma unroll
            for (int r = 0; r < 4; ++r) {
                int row = row0 + wm + i*16 + (lane >> 4)*4 + r;
                size_t idx = (size_t)row * C_ + col;
                float g = bf2f(Gbf[idx]);
                __builtin_nontemporal_store(query[idx] + g * (acc[i][j][r] + bov), &out[idx]);
            }
        }
    }
}

// ---------------------------------------------------------------------------
// MFMA attention, K/V from combined KV buffer [M][512]. (validated r3-r7)
// ---------------------------------------------------------------------------
__device__ inline void stage_v_half(const u16* __restrict__ KV, u16* __restrict__ Vt,
                                    int b, int h, int HF, int tid) {
    #pragma unroll
    for (int i = 0; i < 9; ++i) {
        int c = tid + i*256;
        int k = c >> 3;            // 0..287
        int d0 = (c & 7) * 8;
        union { u32x4 v; u16 s[8]; } u;
        u.v = *(const u32x4*)(KV + ((size_t)(b*N_ + HF*288 + k))*512 + 256 + h*HD_ + d0);
        #pragma unroll
        for (int e = 0; e < 8; ++e)
            Vt[(d0 + e)*296 + k] = u.s[e];
    }
}

template<int HF>
__device__ inline void pv_half(const unsigned (&pk)[36][2], f32x4 (&cacc)[4],
                               const u16* __restrict__ Vt, int lane) {
    int s1 = (lane & 15) + ((lane & 16) << 1);
    int s2 = s1 + 16;
    bool hi = (lane & 32) != 0;
    #pragma unroll
    for (int t9 = 0; t9 < 9; ++t9) {
        const int t = HF*9 + t9;
        unsigned A01 = __shfl((int)pk[2*t  ][0], s1, 64);
        unsigned A23 = __shfl((int)pk[2*t  ][1], s1, 64);
        unsigned B01 = __shfl((int)pk[2*t+1][0], s1, 64);
        unsigned B23 = __shfl((int)pk[2*t+1][1], s1, 64);
        unsigned C01 = __shfl((int)pk[2*t  ][0], s2, 64);
        unsigned C23 = __shfl((int)pk[2*t  ][1], s2, 64);
        unsigned D01 = __shfl((int)pk[2*t+1][0], s2, 64);
        unsigned D23 = __shfl((int)pk[2*t+1][1], s2, 64);
        union { unsigned w[4]; bf16x8 v; } bu;
        bu.w[0] = hi ? B01 : A01;
        bu.w[1] = hi ? B23 : A23;
        bu.w[2] = hi ? D01 : C01;
        bu.w[3] = hi ? D23 : C23;
        int colb = 32*t - 288*HF + 8*(lane >> 4);
        #pragma unroll
        for (int dt = 0; dt < 4; ++dt) {
            bf16x8 a = *(const bf16x8*)&Vt[(16*dt + (lane & 15))*296 + colb];
            cacc[dt] = __builtin_amdgcn_mfma_f32_16x16x32_bf16(a, bu.v, cacc[dt], 0, 0, 0);
        }
    }
}

__global__ __launch_bounds__(256, 2)
void attn_mfma_kernel(const u16* __restrict__ Qbf, const u16* __restrict__ KV,
                      const float* __restrict__ mask,
                      float* __restrict__ attn_out, u16* __restrict__ ctxb) {
    __shared__ u16 Vt[64*296];
    __shared__ float Msk[576];
    int tid = threadIdx.x;
    int lane = tid & 63, wid = tid >> 6;
    int qb, bh;
    xcd_remap<9, 128>(qb, bh);
    int b = bh >> 2, h = bh & 3;
    int q0 = qb * 64;
    int g = lane >> 4;
    int qrow = q0 + wid*16 + (lane & 15);

    if (tid < 144) {
        float4 mv = *(const float4*)(mask + b*N_ + tid*4);
        *(float4*)&Msk[tid*4] = make_float4(ALPHA_*mv.x, ALPHA_*mv.y, ALPHA_*mv.z, ALPHA_*mv.w);
    }
    stage_v_half(KV, Vt, b, h, 0, tid);
    __syncthreads();

    const u16* qp = Qbf + ((size_t)(b*N_) + qrow)*INNER_ + h*HD_ + g*8;
    bf16x8 qf0 = *(const bf16x8*)qp;
    bf16x8 qf1 = *(const bf16x8*)(qp + 32);

    f32x4 acc[36];
    #pragma unroll
    for (int T = 0; T < 36; ++T) acc[T] = (f32x4){0.f, 0.f, 0.f, 0.f};

    const u16* kp = KV + ((size_t)(b*N_) + (lane & 15))*512 + h*HD_ + g*8;
    bf16x8 kb[2][2];
    kb[0][0] = *(const bf16x8*)(kp);
    kb[0][1] = *(const bf16x8*)(kp + 32);
    kb[1][0] = *(const bf16x8*)(kp + 16*512);
    kb[1][1] = *(const bf16x8*)(kp + 16*512 + 32);
    #pragma unroll
    for (int T = 0; T < 36; ++T) {
        bf16x8 n0, n1;
        if (T + 2 < 36) {
            n0 = *(const bf16x8*)(kp + (size_t)(T+2)*16*512);
            n1 = *(const bf16x8*)(kp + (size_t)(T+2)*16*512 + 32);
        }
        acc[T] = __builtin_amdgcn_mfma_f32_16x16x32_bf16(kb[T&1][0], qf0, acc[T], 0, 0, 0);
        acc[T] = __builtin_amdgcn_mfma_f32_16x16x32_bf16(kb[T&1][1], qf1, acc[T], 0, 0, 0);
        if (T + 2 < 36) { kb[T&1][0] = n0; kb[T&1][1] = n1; }
    }

    float m = -1e30f;
    #pragma unroll
    for (int T = 0; T < 36; ++T) {
        float4 mk = *(const float4*)&Msk[16*T + 4*g];
        acc[T][0] = acc[T][0]*0.125f + mk.x;
        acc[T][1] = acc[T][1]*0.125f + mk.y;
        acc[T][2] = acc[T][2]*0.125f + mk.z;
        acc[T][3] = acc[T][3]*0.125f + mk.w;
        m = fmaxf(m, fmaxf(fmaxf(acc[T][0], acc[T][1]), fmaxf(acc[T][2], acc[T][3])));
    }
    m = fmaxf(m, __shfl_xor(m, 16, 64));
    m = fmaxf(m, __shfl_xor(m, 32, 64));

    float l = 0.f;
    #pragma unroll
    for (int T = 0; T < 36; ++T) {
        acc[T][0] = expf(acc[T][0] - m);
        acc[T][1] = expf(acc[T][1] - m);
        acc[T][2] = expf(acc[T][2] - m);
        acc[T][3] = expf(acc[T][3] - m);
        l += acc[T][0] + acc[T][1] + acc[T][2] + acc[T][3];
    }
    l += __shfl_xor(l, 16, 64);
    l += __shfl_xor(l, 32, 64);
    float inv = 1.f / l;

    unsigned pk[36][2];
    float* ap = attn_out + ((size_t)bh*N_ + qrow)*N_;
    #pragma unroll
    for (int T = 0; T < 36; ++T) {
        float e0 = acc[T][0]*inv, e1 = acc[T][1]*inv;
        float e2 = acc[T][2]*inv, e3 = acc[T][3]*inv;
        f32x4 ov = {e0, e1, e2, e3};
        __builtin_nontemporal_store(ov, (f32x4*)(ap + 16*T + 4*g));
        pk[T][0] = pack2bf(e0, e1);
        pk[T][1] = pack2bf(e2, e3);
    }

    f32x4 cacc[4] = {};
    pv_half<0>(pk, cacc, Vt, lane);
    __syncthreads();
    stage_v_half(KV, Vt, b, h, 1, tid);
    __syncthreads();
    pv_half<1>(pk, cacc, Vt, lane);

    u16* cp = ctxb + ((size_t)(b*N_) + qrow)*INNER_ + h*HD_ + 4*g;
    #pragma unroll
    for (int dt = 0; dt < 4; ++dt) {
        ushort4 o;
        o.x = bfbits(cacc[dt][0]);
        o.y = bfbits(cacc[dt][1]);
        o.z = bfbits(cacc[dt][2]);
        o.w = bfbits(cacc[dt][3]);
        *(ushort4*)(cp + 16*dt) = o;
    }
}

// ---------------------------------------------------------------------------
extern "C" void kernel_launch(void* const* d_in, const int* in_sizes, int n_in,
                              void* d_out, int out_size, void* d_ws, size_t ws_size,
                              hipStream_t stream) {
    const float* query   = (const float*)d_in[0];
    const float* support = (const float*)d_in[1];
    const float* mask    = (const float*)d_in[2];
    const float* ln_q_w  = (const float*)d_in[3];
    const float* ln_q_b  = (const float*)d_in[4];
    const float* ln_s_w  = (const float*)d_in[5];
    const float* ln_s_b  = (const float*)d_in[6];
    const float* Wq      = (const float*)d_in[7];
    const float* bq      = (const float*)d_in[8];
    const float* Wk      = (const float*)d_in[9];
    const float* bk      = (const float*)d_in[10];
    const float* Wv      = (const float*)d_in[11];
    const float* bv      = (const float*)d_in[12];
    const float* Wo      = (const float*)d_in[13];
    const float* bo      = (const float*)d_in[14];
    const float* Wg      = (const float*)d_in[15];
    const float* bg      = (const float*)d_in[16];

    float* out      = (float*)d_out;
    float* attn_out = out + (size_t)M_ * C_;

    char* w = (char*)d_ws;
    u16* Aq    = (u16*)w;  w += (size_t)M_*C_*2;
    u16* As_   = (u16*)w;  w += (size_t)M_*C_*2;
    u16* Xq    = (u16*)w;  w += (size_t)M_*C_*2;
    u16* Wall  = (u16*)w;  w += (size_t)1792*C_*2;
    u16* Wo_b  = (u16*)w;  w += (size_t)C_*INNER_*2;
    u16* Qbf   = (u16*)w;  w += (size_t)M_*INNER_*2;
    u16* KVbf  = (u16*)w;  w += (size_t)M_*2*INNER_*2;
    u16* Gbf   = (u16*)w;  w += (size_t)M_*C_*2;
    u16* ctxb  = (u16*)w;  w += (size_t)M_*INNER_*2;

    // Fused LN for both tensors; query pass also emits raw bf16 (Xq)
    ln_fused2_kernel<<<dim3(M_/4, 2), dim3(256), 0, stream>>>(
        query, support, ln_q_w, ln_q_b, ln_s_w, ln_s_b, Aq, As_, Xq);

    // Weight conversions into combined Wall + Wo_b
    cvt_weights_kernel<<<dim3(1024), dim3(256), 0, stream>>>(
        Wq, Wk, Wv, Wo, Wg, Wall, Wo_b);

    // Q + KV + gate in one 256x128-tile GEMM
    mega_gemm_kernel<<<dim3(14, 72), dim3(512), 0, stream>>>(
        Aq, As_, Xq, Wall, bq, bk, bv, bg, Qbf, KVbf, Gbf);

    // attention
    attn_mfma_kernel<<<dim3(N_/64, B_*H_), dim3(256), 0, stream>>>(
        Qbf, KVbf, mask, attn_out, ctxb);

    // out = query + gate * (ctx@Wo^T + bo)
    final_lite_kernel<<<dim3(8, 144), dim3(256), 0, stream>>>(
        query, Gbf, ctxb, Wo_b, bo, out);
}

// Round 10
// 388.748 us; speedup vs baseline: 1.0119x; 1.0119x over previous
//
#include <hip/hip_runtime.h>
#include <hip/hip_bf16.h>
#include <math.h>

#define B_ 32
#define N_ 576
#define C_ 1024
#define INNER_ 256
#define H_ 4
#define HD_ 64
#define M_ (B_*N_)           // 18432
#define ALPHA_ 5.0f
#define EPS_ 1e-5f

typedef __attribute__((ext_vector_type(8))) short bf16x8;
typedef __attribute__((ext_vector_type(4))) float f32x4;
typedef __attribute__((ext_vector_type(4))) unsigned int u32x4;
typedef unsigned short u16;

__device__ inline u16 bfbits(float x) {
    union { __hip_bfloat16 h; u16 u; } c; c.h = __float2bfloat16(x); return c.u;
}
__device__ inline float bf2f(u16 u) {
    union { unsigned u32; float f; } c; c.u32 = ((unsigned)u) << 16; return c.f;
}
__device__ inline unsigned pack2bf(float a, float b) {
    return (unsigned)bfbits(a) | ((unsigned)bfbits(b) << 16);
}

// Async global->LDS, 16B per lane. LDS dest: wave-uniform base + lane*16.
__device__ __forceinline__ void gld16(void* lds, const void* g) {
    __builtin_amdgcn_global_load_lds(
        (const __attribute__((address_space(1))) unsigned int*)g,
        (__attribute__((address_space(3))) unsigned int*)lds, 16, 0, 0);
}

// XCD row-clustering swizzle (bijective when GY % 8 == 0).
template<int GX, int GY>
__device__ inline void xcd_remap(int& col, int& row) {
    int f = blockIdx.y * GX + blockIdx.x;
    int xcd = f & 7;
    int slot = f >> 3;
    col = slot % GX;
    row = xcd * (GY >> 3) + slot / GX;
}

// ---------------------------------------------------------------------------
// Fused LayerNorm for both tensors; query pass (blockIdx.y==0) also emits the
// raw input as bf16 (Xq) for the gate GEMM.
// ---------------------------------------------------------------------------
__global__ void ln_fused2_kernel(const float* __restrict__ Xq, const float* __restrict__ Xs,
                                 const float* __restrict__ wq, const float* __restrict__ bq,
                                 const float* __restrict__ ws, const float* __restrict__ bs,
                                 u16* __restrict__ outq, u16* __restrict__ outs,
                                 u16* __restrict__ outraw) {
    const float* X; const float* w; const float* b; u16* o;
    bool raw = (blockIdx.y == 0);
    if (raw) { X = Xq; w = wq; b = bq; o = outq; }
    else     { X = Xs; w = ws; b = bs; o = outs; }
    int row = blockIdx.x * 4 + (threadIdx.x >> 6);
    int lane = threadIdx.x & 63;
    const float* xp = X + (size_t)row * C_;
    float4 v[4];
    #pragma unroll
    for (int j = 0; j < 4; ++j) v[j] = *(const float4*)(xp + lane*4 + j*256);
    float s = 0.f, s2 = 0.f;
    #pragma unroll
    for (int j = 0; j < 4; ++j) {
        s  += v[j].x + v[j].y + v[j].z + v[j].w;
        s2 += v[j].x*v[j].x + v[j].y*v[j].y + v[j].z*v[j].z + v[j].w*v[j].w;
    }
    #pragma unroll
    for (int m = 32; m; m >>= 1) {
        s  += __shfl_xor(s,  m, 64);
        s2 += __shfl_xor(s2, m, 64);
    }
    float mean = s * (1.f/C_);
    float rs = rsqrtf(s2 * (1.f/C_) - mean*mean + EPS_);
    #pragma unroll
    for (int j = 0; j < 4; ++j) {
        int k = lane*4 + j*256;
        float4 wv = *(const float4*)(w + k);
        float4 bv = *(const float4*)(b + k);
        ushort4 ov;
        ov.x = bfbits((v[j].x - mean)*rs*wv.x + bv.x);
        ov.y = bfbits((v[j].y - mean)*rs*wv.y + bv.y);
        ov.z = bfbits((v[j].z - mean)*rs*wv.z + bv.z);
        ov.w = bfbits((v[j].w - mean)*rs*wv.w + bv.w);
        *(ushort4*)(o + (size_t)row*C_ + k) = ov;
        if (raw) {
            ushort4 r4;
            r4.x = bfbits(v[j].x); r4.y = bfbits(v[j].y);
            r4.z = bfbits(v[j].z); r4.w = bfbits(v[j].w);
            *(ushort4*)(outraw + (size_t)row*C_ + k) = r4;
        }
    }
}

// ---------------------------------------------------------------------------
// Weight conversions: Wall[1792][1024] = Wq|Wk|Wv|Wg rows, Wo_b separate.
// ---------------------------------------------------------------------------
__global__ void cvt_weights_kernel(const float* __restrict__ Wq, const float* __restrict__ Wk,
                                   const float* __restrict__ Wv, const float* __restrict__ Wo,
                                   const float* __restrict__ Wg,
                                   u16* __restrict__ Wall, u16* __restrict__ Wo_b) {
    int g = blockIdx.x * 256 + threadIdx.x;
    const float* src; u16* dst; size_t off;
    if (g < 32768)       { src = Wq; dst = Wall;          off = (size_t)g*8; }
    else if (g < 65536)  { src = Wk; dst = Wall + 262144; off = (size_t)(g-32768)*8; }
    else if (g < 98304)  { src = Wv; dst = Wall + 524288; off = (size_t)(g-65536)*8; }
    else if (g < 131072) { src = Wo; dst = Wo_b;          off = (size_t)(g-98304)*8; }
    else                 { src = Wg; dst = Wall + 786432; off = (size_t)(g-131072)*8; }
    float4 a0 = *(const float4*)(src + off);
    float4 a1 = *(const float4*)(src + off + 4);
    union { u16 s[8]; u32x4 v; } o;
    o.s[0] = bfbits(a0.x); o.s[1] = bfbits(a0.y); o.s[2] = bfbits(a0.z); o.s[3] = bfbits(a0.w);
    o.s[4] = bfbits(a1.x); o.s[5] = bfbits(a1.y); o.s[6] = bfbits(a1.z); o.s[7] = bfbits(a1.w);
    *(u32x4*)(dst + off) = o.v;
}

// ---------------------------------------------------------------------------
// m97-faithful async GEMM inner: 128x128 tile, BK=64, 4 waves, 4x4 frags.
// Linear [128][64] LDS, gld16 staging (4 A + 4 B per thread per K-step),
// 32 MFMA/wave between barriers.
// ---------------------------------------------------------------------------
template<int KDIM>
__device__ __forceinline__ void accum_async(const u16* __restrict__ A,
                                            const u16* __restrict__ Bw,
                                            int row0, int tid, int lane,
                                            int wm, int wn,
                                            u16* __restrict__ Asm, u16* __restrict__ Bsm,
                                            f32x4 (&acc)[4][4]) {
    int rb = tid >> 3;              // 0..31
    int cg = (tid & 7) * 8;         // 0..56
    for (int k0 = 0; k0 < KDIM; k0 += 64) {
        #pragma unroll
        for (int p = 0; p < 4; ++p) {
            gld16(Asm + ((size_t)(p*256 + tid))*8,
                  A + (size_t)(row0 + p*32 + rb)*KDIM + k0 + cg);
            gld16(Bsm + ((size_t)(p*256 + tid))*8,
                  Bw + (size_t)(p*32 + rb)*KDIM + k0 + cg);
        }
        __syncthreads();
        #pragma unroll
        for (int ks = 0; ks < 64; ks += 32) {
            bf16x8 af[4], bfr[4];
            #pragma unroll
            for (int i = 0; i < 4; ++i)
                af[i] = *(const bf16x8*)&Asm[(wm + i*16 + (lane & 15))*64 + ks + (lane >> 4)*8];
            #pragma unroll
            for (int j = 0; j < 4; ++j)
                bfr[j] = *(const bf16x8*)&Bsm[(wn + j*16 + (lane & 15))*64 + ks + (lane >> 4)*8];
            #pragma unroll
            for (int i = 0; i < 4; ++i)
                #pragma unroll
                for (int j = 0; j < 4; ++j)
                    acc[i][j] = __builtin_amdgcn_mfma_f32_16x16x32_bf16(
                        af[i], bfr[j], acc[i][j], 0, 0, 0);
        }
        __syncthreads();
    }
}

// ---------------------------------------------------------------------------
// Q + KV projections. grid (6,144): col-blocks 0-1 = Q, 2-5 = KV.
// ---------------------------------------------------------------------------
__global__ __launch_bounds__(256, 2)
void qkv_gemm_kernel(const u16* __restrict__ Aq, const u16* __restrict__ As,
                     const u16* __restrict__ Wall,
                     const float* __restrict__ bq, const float* __restrict__ bk,
                     const float* __restrict__ bv,
                     u16* __restrict__ Qbf, u16* __restrict__ KVbf) {
    __shared__ u16 Asm[128*64];
    __shared__ u16 Bsm[128*64];
    int tid = threadIdx.x;
    int lane = tid & 63, wid = tid >> 6;
    int wm = (wid >> 1) * 64, wn = (wid & 1) * 64;
    int bc, br;
    xcd_remap<6, 144>(bc, br);
    int row0 = br * 128;
    bool isQ = (bc < 2);
    int colQ = (isQ ? bc : bc - 2) * 128;          // col offset within output
    int wrow0 = isQ ? colQ : 256 + colQ;           // row offset in Wall
    const u16* A = isQ ? Aq : As;
    f32x4 acc[4][4] = {};
    accum_async<C_>(A, Wall + (size_t)wrow0 * C_, row0, tid, lane, wm, wn, Asm, Bsm, acc);
    #pragma unroll
    for (int j = 0; j < 4; ++j) {
        int col = colQ + wn + j*16 + (lane & 15);
        float bb = isQ ? bq[col] : (col < 256 ? bk[col] : bv[col - 256]);
        #pragma unroll
        for (int i = 0; i < 4; ++i) {
            #pragma unroll
            for (int r = 0; r < 4; ++r) {
                int row = row0 + wm + i*16 + (lane >> 4)*4 + r;
                float v = acc[i][j][r] + bb;
                if (isQ) Qbf[(size_t)row*256 + col] = bfbits(v);
                else     KVbf[(size_t)row*512 + col] = bfbits(v);
            }
        }
    }
}

// ---------------------------------------------------------------------------
// Gate GEMM: Gbf = sigmoid(Xq @ Wg^T + bg), bf16 out. grid (8,144).
// ---------------------------------------------------------------------------
__global__ __launch_bounds__(256, 2)
void gate_gemm_kernel(const u16* __restrict__ Xq, const u16* __restrict__ Wg_rows,
                      const float* __restrict__ bg, u16* __restrict__ Gbf) {
    __shared__ u16 Asm[128*64];
    __shared__ u16 Bsm[128*64];
    int tid = threadIdx.x;
    int lane = tid & 63, wid = tid >> 6;
    int wm = (wid >> 1) * 64, wn = (wid & 1) * 64;
    int bc, br;
    xcd_remap<8, 144>(bc, br);
    int row0 = br * 128, col0 = bc * 128;
    f32x4 acc[4][4] = {};
    accum_async<C_>(Xq, Wg_rows + (size_t)col0 * C_, row0, tid, lane, wm, wn, Asm, Bsm, acc);
    #pragma unroll
    for (int j = 0; j < 4; ++j) {
        int col = col0 + wn + j*16 + (lane & 15);
        float bb = bg[col];
        #pragma unroll
        for (int i = 0; i < 4; ++i) {
            #pragma unroll
            for (int r = 0; r < 4; ++r) {
                int row = row0 + wm + i*16 + (lane >> 4)*4 + r;
                float v = acc[i][j][r] + bb;
                Gbf[(size_t)row*1024 + col] = bfbits(1.f / (1.f + expf(-v)));
            }
        }
    }
}

// ---------------------------------------------------------------------------
// final_lite: out = query + gate * (ctx@Wo^T + bo). K=256, 128x128 tile,
// reg-staged padded LDS (r6/r9-validated structure).
// ---------------------------------------------------------------------------
__global__ __launch_bounds__(256, 2)
void final_lite_kernel(const float* __restrict__ query, const u16* __restrict__ Gbf,
                       const u16* __restrict__ ctxb, const u16* __restrict__ Wo_b,
                       const float* __restrict__ bo, float* __restrict__ out) {
    __shared__ u16 Asm[128][72];
    __shared__ u16 Bsm[128][72];
    int tid = threadIdx.x;
    int lane = tid & 63, wid = tid >> 6;
    int wm = (wid >> 1) * 64, wn = (wid & 1) * 64;
    int bc, br;
    xcd_remap<8, 144>(bc, br);
    int row0 = br * 128, col0 = bc * 128;
    f32x4 acc[4][4] = {};
    for (int k0 = 0; k0 < INNER_; k0 += 64) {
        #pragma unroll
        for (int i = 0; i < 4; ++i) {
            int s = tid + i*256;
            int r = s >> 3, cg = (s & 7) * 8;
            *(u32x4*)&Asm[r][cg] = *(const u32x4*)(ctxb + (size_t)(row0 + r)*INNER_ + k0 + cg);
            *(u32x4*)&Bsm[r][cg] = *(const u32x4*)(Wo_b + (size_t)(col0 + r)*INNER_ + k0 + cg);
        }
        __syncthreads();
        #pragma unroll
        for (int ks = 0; ks < 64; ks += 32) {
            bf16x8 af[4], bfr[4];
            #pragma unroll
            for (int i = 0; i < 4; ++i)
                af[i] = *(const bf16x8*)&Asm[wm + i*16 + (lane & 15)][ks + (lane >> 4)*8];
            #pragma unroll
            for (int j = 0; j < 4; ++j)
                bfr[j] = *(const bf16x8*)&Bsm[wn + j*16 + (lane & 15)][ks + (lane >> 4)*8];
            #pragma unroll
            for (int i = 0; i < 4; ++i)
                #pragma unroll
                for (int j = 0; j < 4; ++j)
                    acc[i][j] = __builtin_amdgcn_mfma_f32_16x16x32_bf16(
                        af[i], bfr[j], acc[i][j], 0, 0, 0);
        }
        __syncthreads();
    }
    #pragma unroll
    for (int i = 0; i < 4; ++i) {
        #pragma unroll
        for (int j = 0; j < 4; ++j) {
            int col = col0 + wn + j*16 + (lane & 15);
            float bov = bo[col];
            #pragma unroll
            for (int r = 0; r < 4; ++r) {
                int row = row0 + wm + i*16 + (lane >> 4)*4 + r;
                size_t idx = (size_t)row * C_ + col;
                float g = bf2f(Gbf[idx]);
                __builtin_nontemporal_store(query[idx] + g * (acc[i][j][r] + bov), &out[idx]);
            }
        }
    }
}

// ---------------------------------------------------------------------------
// MFMA attention, K/V from combined KV buffer [M][512]. (validated r3-r9)
// ---------------------------------------------------------------------------
__device__ inline void stage_v_half(const u16* __restrict__ KV, u16* __restrict__ Vt,
                                    int b, int h, int HF, int tid) {
    #pragma unroll
    for (int i = 0; i < 9; ++i) {
        int c = tid + i*256;
        int k = c >> 3;            // 0..287
        int d0 = (c & 7) * 8;
        union { u32x4 v; u16 s[8]; } u;
        u.v = *(const u32x4*)(KV + ((size_t)(b*N_ + HF*288 + k))*512 + 256 + h*HD_ + d0);
        #pragma unroll
        for (int e = 0; e < 8; ++e)
            Vt[(d0 + e)*296 + k] = u.s[e];
    }
}

template<int HF>
__device__ inline void pv_half(const unsigned (&pk)[36][2], f32x4 (&cacc)[4],
                               const u16* __restrict__ Vt, int lane) {
    int s1 = (lane & 15) + ((lane & 16) << 1);
    int s2 = s1 + 16;
    bool hi = (lane & 32) != 0;
    #pragma unroll
    for (int t9 = 0; t9 < 9; ++t9) {
        const int t = HF*9 + t9;
        unsigned A01 = __shfl((int)pk[2*t  ][0], s1, 64);
        unsigned A23 = __shfl((int)pk[2*t  ][1], s1, 64);
        unsigned B01 = __shfl((int)pk[2*t+1][0], s1, 64);
        unsigned B23 = __shfl((int)pk[2*t+1][1], s1, 64);
        unsigned C01 = __shfl((int)pk[2*t  ][0], s2, 64);
        unsigned C23 = __shfl((int)pk[2*t  ][1], s2, 64);
        unsigned D01 = __shfl((int)pk[2*t+1][0], s2, 64);
        unsigned D23 = __shfl((int)pk[2*t+1][1], s2, 64);
        union { unsigned w[4]; bf16x8 v; } bu;
        bu.w[0] = hi ? B01 : A01;
        bu.w[1] = hi ? B23 : A23;
        bu.w[2] = hi ? D01 : C01;
        bu.w[3] = hi ? D23 : C23;
        int colb = 32*t - 288*HF + 8*(lane >> 4);
        #pragma unroll
        for (int dt = 0; dt < 4; ++dt) {
            bf16x8 a = *(const bf16x8*)&Vt[(16*dt + (lane & 15))*296 + colb];
            cacc[dt] = __builtin_amdgcn_mfma_f32_16x16x32_bf16(a, bu.v, cacc[dt], 0, 0, 0);
        }
    }
}

__global__ __launch_bounds__(256, 2)
void attn_mfma_kernel(const u16* __restrict__ Qbf, const u16* __restrict__ KV,
                      const float* __restrict__ mask,
                      float* __restrict__ attn_out, u16* __restrict__ ctxb) {
    __shared__ u16 Vt[64*296];
    __shared__ float Msk[576];
    int tid = threadIdx.x;
    int lane = tid & 63, wid = tid >> 6;
    int qb, bh;
    xcd_remap<9, 128>(qb, bh);
    int b = bh >> 2, h = bh & 3;
    int q0 = qb * 64;
    int g = lane >> 4;
    int qrow = q0 + wid*16 + (lane & 15);

    if (tid < 144) {
        float4 mv = *(const float4*)(mask + b*N_ + tid*4);
        *(float4*)&Msk[tid*4] = make_float4(ALPHA_*mv.x, ALPHA_*mv.y, ALPHA_*mv.z, ALPHA_*mv.w);
    }
    stage_v_half(KV, Vt, b, h, 0, tid);
    __syncthreads();

    const u16* qp = Qbf + ((size_t)(b*N_) + qrow)*INNER_ + h*HD_ + g*8;
    bf16x8 qf0 = *(const bf16x8*)qp;
    bf16x8 qf1 = *(const bf16x8*)(qp + 32);

    f32x4 acc[36];
    #pragma unroll
    for (int T = 0; T < 36; ++T) acc[T] = (f32x4){0.f, 0.f, 0.f, 0.f};

    const u16* kp = KV + ((size_t)(b*N_) + (lane & 15))*512 + h*HD_ + g*8;
    bf16x8 kb[2][2];
    kb[0][0] = *(const bf16x8*)(kp);
    kb[0][1] = *(const bf16x8*)(kp + 32);
    kb[1][0] = *(const bf16x8*)(kp + 16*512);
    kb[1][1] = *(const bf16x8*)(kp + 16*512 + 32);
    #pragma unroll
    for (int T = 0; T < 36; ++T) {
        bf16x8 n0, n1;
        if (T + 2 < 36) {
            n0 = *(const bf16x8*)(kp + (size_t)(T+2)*16*512);
            n1 = *(const bf16x8*)(kp + (size_t)(T+2)*16*512 + 32);
        }
        acc[T] = __builtin_amdgcn_mfma_f32_16x16x32_bf16(kb[T&1][0], qf0, acc[T], 0, 0, 0);
        acc[T] = __builtin_amdgcn_mfma_f32_16x16x32_bf16(kb[T&1][1], qf1, acc[T], 0, 0, 0);
        if (T + 2 < 36) { kb[T&1][0] = n0; kb[T&1][1] = n1; }
    }

    float m = -1e30f;
    #pragma unroll
    for (int T = 0; T < 36; ++T) {
        float4 mk = *(const float4*)&Msk[16*T + 4*g];
        acc[T][0] = acc[T][0]*0.125f + mk.x;
        acc[T][1] = acc[T][1]*0.125f + mk.y;
        acc[T][2] = acc[T][2]*0.125f + mk.z;
        acc[T][3] = acc[T][3]*0.125f + mk.w;
        m = fmaxf(m, fmaxf(fmaxf(acc[T][0], acc[T][1]), fmaxf(acc[T][2], acc[T][3])));
    }
    m = fmaxf(m, __shfl_xor(m, 16, 64));
    m = fmaxf(m, __shfl_xor(m, 32, 64));

    float l = 0.f;
    #pragma unroll
    for (int T = 0; T < 36; ++T) {
        acc[T][0] = expf(acc[T][0] - m);
        acc[T][1] = expf(acc[T][1] - m);
        acc[T][2] = expf(acc[T][2] - m);
        acc[T][3] = expf(acc[T][3] - m);
        l += acc[T][0] + acc[T][1] + acc[T][2] + acc[T][3];
    }
    l += __shfl_xor(l, 16, 64);
    l += __shfl_xor(l, 32, 64);
    float inv = 1.f / l;

    unsigned pk[36][2];
    float* ap = attn_out + ((size_t)bh*N_ + qrow)*N_;
    #pragma unroll
    for (int T = 0; T < 36; ++T) {
        float e0 = acc[T][0]*inv, e1 = acc[T][1]*inv;
        float e2 = acc[T][2]*inv, e3 = acc[T][3]*inv;
        f32x4 ov = {e0, e1, e2, e3};
        __builtin_nontemporal_store(ov, (f32x4*)(ap + 16*T + 4*g));
        pk[T][0] = pack2bf(e0, e1);
        pk[T][1] = pack2bf(e2, e3);
    }

    f32x4 cacc[4] = {};
    pv_half<0>(pk, cacc, Vt, lane);
    __syncthreads();
    stage_v_half(KV, Vt, b, h, 1, tid);
    __syncthreads();
    pv_half<1>(pk, cacc, Vt, lane);

    u16* cp = ctxb + ((size_t)(b*N_) + qrow)*INNER_ + h*HD_ + 4*g;
    #pragma unroll
    for (int dt = 0; dt < 4; ++dt) {
        ushort4 o;
        o.x = bfbits(cacc[dt][0]);
        o.y = bfbits(cacc[dt][1]);
        o.z = bfbits(cacc[dt][2]);
        o.w = bfbits(cacc[dt][3]);
        *(ushort4*)(cp + 16*dt) = o;
    }
}

// ---------------------------------------------------------------------------
extern "C" void kernel_launch(void* const* d_in, const int* in_sizes, int n_in,
                              void* d_out, int out_size, void* d_ws, size_t ws_size,
                              hipStream_t stream) {
    const float* query   = (const float*)d_in[0];
    const float* support = (const float*)d_in[1];
    const float* mask    = (const float*)d_in[2];
    const float* ln_q_w  = (const float*)d_in[3];
    const float* ln_q_b  = (const float*)d_in[4];
    const float* ln_s_w  = (const float*)d_in[5];
    const float* ln_s_b  = (const float*)d_in[6];
    const float* Wq      = (const float*)d_in[7];
    const float* bq      = (const float*)d_in[8];
    const float* Wk      = (const float*)d_in[9];
    const float* bk      = (const float*)d_in[10];
    const float* Wv      = (const float*)d_in[11];
    const float* bv      = (const float*)d_in[12];
    const float* Wo      = (const float*)d_in[13];
    const float* bo      = (const float*)d_in[14];
    const float* Wg      = (const float*)d_in[15];
    const float* bg      = (const float*)d_in[16];

    float* out      = (float*)d_out;
    float* attn_out = out + (size_t)M_ * C_;

    char* w = (char*)d_ws;
    u16* Aq    = (u16*)w;  w += (size_t)M_*C_*2;
    u16* As_   = (u16*)w;  w += (size_t)M_*C_*2;
    u16* Xq    = (u16*)w;  w += (size_t)M_*C_*2;
    u16* Wall  = (u16*)w;  w += (size_t)1792*C_*2;
    u16* Wo_b  = (u16*)w;  w += (size_t)C_*INNER_*2;
    u16* Qbf   = (u16*)w;  w += (size_t)M_*INNER_*2;
    u16* KVbf  = (u16*)w;  w += (size_t)M_*2*INNER_*2;
    u16* Gbf   = (u16*)w;  w += (size_t)M_*C_*2;
    u16* ctxb  = (u16*)w;  w += (size_t)M_*INNER_*2;

    // Fused LN for both tensors; query pass also emits raw bf16 (Xq)
    ln_fused2_kernel<<<dim3(M_/4, 2), dim3(256), 0, stream>>>(
        query, support, ln_q_w, ln_q_b, ln_s_w, ln_s_b, Aq, As_, Xq);

    // Weight conversions into combined Wall + Wo_b
    cvt_weights_kernel<<<dim3(1024), dim3(256), 0, stream>>>(
        Wq, Wk, Wv, Wo, Wg, Wall, Wo_b);

    // Q + KV projections (async m97 structure)
    qkv_gemm_kernel<<<dim3(6, 144), dim3(256), 0, stream>>>(
        Aq, As_, Wall, bq, bk, bv, Qbf, KVbf);

    // gate = sigmoid(Xq @ Wg^T + bg) (async m97 structure)
    gate_gemm_kernel<<<dim3(8, 144), dim3(256), 0, stream>>>(
        Xq, Wall + (size_t)768 * C_, bg, Gbf);

    // attention
    attn_mfma_kernel<<<dim3(N_/64, B_*H_), dim3(256), 0, stream>>>(
        Qbf, KVbf, mask, attn_out, ctxb);

    // out = query + gate * (ctx@Wo^T + bo)
    final_lite_kernel<<<dim3(8, 144), dim3(256), 0, stream>>>(
        query, Gbf, ctxb, Wo_b, bo, out);
}

// Round 11
// 324.691 us; speedup vs baseline: 1.2115x; 1.1973x over previous
//
#include <hip/hip_runtime.h>
#include <hip/hip_bf16.h>
#include <math.h>

#define B_ 32
#define N_ 576
#define C_ 1024
#define INNER_ 256
#define H_ 4
#define HD_ 64
#define M_ (B_*N_)           // 18432
#define ALPHA_ 5.0f
#define EPS_ 1e-5f

typedef __attribute__((ext_vector_type(8))) short bf16x8;
typedef __attribute__((ext_vector_type(4))) float f32x4;
typedef __attribute__((ext_vector_type(4))) unsigned int u32x4;
typedef unsigned short u16;

__device__ inline u16 bfbits(float x) {
    union { __hip_bfloat16 h; u16 u; } c; c.h = __float2bfloat16(x); return c.u;
}
__device__ inline float bf2f(u16 u) {
    union { unsigned u32; float f; } c; c.u32 = ((unsigned)u) << 16; return c.f;
}
__device__ inline unsigned pack2bf(float a, float b) {
    return (unsigned)bfbits(a) | ((unsigned)bfbits(b) << 16);
}

// Async global->LDS, 16B per lane. LDS dest: wave-uniform base + lane*16.
__device__ __forceinline__ void gld16(void* lds, const void* g) {
    __builtin_amdgcn_global_load_lds(
        (const __attribute__((address_space(1))) unsigned int*)g,
        (__attribute__((address_space(3))) unsigned int*)lds, 16, 0, 0);
}

// XCD row-clustering swizzle (bijective when GX*GY % 8 == 0).
template<int GX, int GY>
__device__ inline void xcd_remap(int& col, int& row) {
    int f = blockIdx.y * GX + blockIdx.x;
    int xcd = f & 7;
    int slot = f >> 3;
    col = slot % GX;
    row = xcd * (GY >> 3) + slot / GX;
}

// ---------------------------------------------------------------------------
// Fused LayerNorm for both tensors; query pass (blockIdx.y==0) also emits the
// raw input as bf16 (Xq) for the gate GEMM.
// ---------------------------------------------------------------------------
__global__ void ln_fused2_kernel(const float* __restrict__ Xq, const float* __restrict__ Xs,
                                 const float* __restrict__ wq, const float* __restrict__ bq,
                                 const float* __restrict__ ws, const float* __restrict__ bs,
                                 u16* __restrict__ outq, u16* __restrict__ outs,
                                 u16* __restrict__ outraw) {
    const float* X; const float* w; const float* b; u16* o;
    bool raw = (blockIdx.y == 0);
    if (raw) { X = Xq; w = wq; b = bq; o = outq; }
    else     { X = Xs; w = ws; b = bs; o = outs; }
    int row = blockIdx.x * 4 + (threadIdx.x >> 6);
    int lane = threadIdx.x & 63;
    const float* xp = X + (size_t)row * C_;
    float4 v[4];
    #pragma unroll
    for (int j = 0; j < 4; ++j) v[j] = *(const float4*)(xp + lane*4 + j*256);
    float s = 0.f, s2 = 0.f;
    #pragma unroll
    for (int j = 0; j < 4; ++j) {
        s  += v[j].x + v[j].y + v[j].z + v[j].w;
        s2 += v[j].x*v[j].x + v[j].y*v[j].y + v[j].z*v[j].z + v[j].w*v[j].w;
    }
    #pragma unroll
    for (int m = 32; m; m >>= 1) {
        s  += __shfl_xor(s,  m, 64);
        s2 += __shfl_xor(s2, m, 64);
    }
    float mean = s * (1.f/C_);
    float rs = rsqrtf(s2 * (1.f/C_) - mean*mean + EPS_);
    #pragma unroll
    for (int j = 0; j < 4; ++j) {
        int k = lane*4 + j*256;
        float4 wv = *(const float4*)(w + k);
        float4 bv = *(const float4*)(b + k);
        ushort4 ov;
        ov.x = bfbits((v[j].x - mean)*rs*wv.x + bv.x);
        ov.y = bfbits((v[j].y - mean)*rs*wv.y + bv.y);
        ov.z = bfbits((v[j].z - mean)*rs*wv.z + bv.z);
        ov.w = bfbits((v[j].w - mean)*rs*wv.w + bv.w);
        *(ushort4*)(o + (size_t)row*C_ + k) = ov;
        if (raw) {
            ushort4 r4;
            r4.x = bfbits(v[j].x); r4.y = bfbits(v[j].y);
            r4.z = bfbits(v[j].z); r4.w = bfbits(v[j].w);
            *(ushort4*)(outraw + (size_t)row*C_ + k) = r4;
        }
    }
}

// ---------------------------------------------------------------------------
// Weight conversions: Wall[1792][1024] = Wq|Wk|Wv|Wg rows, Wo_b separate.
// ---------------------------------------------------------------------------
__global__ void cvt_weights_kernel(const float* __restrict__ Wq, const float* __restrict__ Wk,
                                   const float* __restrict__ Wv, const float* __restrict__ Wo,
                                   const float* __restrict__ Wg,
                                   u16* __restrict__ Wall, u16* __restrict__ Wo_b) {
    int g = blockIdx.x * 256 + threadIdx.x;
    const float* src; u16* dst; size_t off;
    if (g < 32768)       { src = Wq; dst = Wall;          off = (size_t)g*8; }
    else if (g < 65536)  { src = Wk; dst = Wall + 262144; off = (size_t)(g-32768)*8; }
    else if (g < 98304)  { src = Wv; dst = Wall + 524288; off = (size_t)(g-65536)*8; }
    else if (g < 131072) { src = Wo; dst = Wo_b;          off = (size_t)(g-98304)*8; }
    else                 { src = Wg; dst = Wall + 786432; off = (size_t)(g-131072)*8; }
    float4 a0 = *(const float4*)(src + off);
    float4 a1 = *(const float4*)(src + off + 4);
    union { u16 s[8]; u32x4 v; } o;
    o.s[0] = bfbits(a0.x); o.s[1] = bfbits(a0.y); o.s[2] = bfbits(a0.z); o.s[3] = bfbits(a0.w);
    o.s[4] = bfbits(a1.x); o.s[5] = bfbits(a1.y); o.s[6] = bfbits(a1.z); o.s[7] = bfbits(a1.w);
    *(u32x4*)(dst + off) = o.v;
}

// ---------------------------------------------------------------------------
// Swizzled async staging (rule #21 involution): LDS dest linear (lane*16),
// global SOURCE pre-swizzled by chunk ^= (row&7); ds_read applies the same
// XOR -> bank-conflict-free reads. 1024 x 16B slots per matrix per buffer.
// ---------------------------------------------------------------------------
__device__ __forceinline__ void stage_swz(const u16* __restrict__ G, int ld,
                                          int row_base, int k0,
                                          u16* __restrict__ lds, int tid) {
    #pragma unroll
    for (int p = 0; p < 4; ++p) {
        int s = p*256 + tid;          // slot 0..1023
        int r = s >> 3;               // row 0..127
        int pc = s & 7;               // physical 16B chunk
        int c  = pc ^ (r & 7);        // logical chunk stored here
        gld16(lds + (size_t)s*8, G + (size_t)(row_base + r)*ld + k0 + c*8);
    }
}

// compute one BK=64 step from a staged buffer pair (swizzled reads)
__device__ __forceinline__ void compute_step(const u16* __restrict__ Asm,
                                             const u16* __restrict__ Bsm,
                                             int lane, int wm, int wn,
                                             f32x4 (&acc)[4][4]) {
    #pragma unroll
    for (int ks = 0; ks < 64; ks += 32) {
        bf16x8 af[4], bfr[4];
        #pragma unroll
        for (int i = 0; i < 4; ++i) {
            int ra = wm + i*16 + (lane & 15);
            int ca = (ks >> 3) + (lane >> 4);
            af[i] = *(const bf16x8*)&Asm[ra*64 + ((ca ^ (ra & 7)) << 3)];
        }
        #pragma unroll
        for (int j = 0; j < 4; ++j) {
            int rb = wn + j*16 + (lane & 15);
            int cb = (ks >> 3) + (lane >> 4);
            bfr[j] = *(const bf16x8*)&Bsm[rb*64 + ((cb ^ (rb & 7)) << 3)];
        }
        #pragma unroll
        for (int i = 0; i < 4; ++i)
            #pragma unroll
            for (int j = 0; j < 4; ++j)
                acc[i][j] = __builtin_amdgcn_mfma_f32_16x16x32_bf16(
                    af[i], bfr[j], acc[i][j], 0, 0, 0);
    }
}

// 2-phase double-buffered K-loop. LDS: AsmL/BsmL are [2][8192] u16.
template<int KDIM>
__device__ __forceinline__ void accum_pipe(const u16* __restrict__ A, int lda, int row0,
                                           const u16* __restrict__ Bw, int ldb,
                                           u16* __restrict__ AsmL, u16* __restrict__ BsmL,
                                           int tid, int lane, int wm, int wn,
                                           f32x4 (&acc)[4][4]) {
    const int NT = KDIM / 64;
    stage_swz(A,  lda, row0, 0, AsmL, tid);
    stage_swz(Bw, ldb, 0,    0, BsmL, tid);
    __syncthreads();
    int cur = 0;
    for (int t = 0; t + 1 < NT; ++t) {
        int nxt = cur ^ 1;
        stage_swz(A,  lda, row0, (t+1)*64, AsmL + nxt*8192, tid);
        stage_swz(Bw, ldb, 0,    (t+1)*64, BsmL + nxt*8192, tid);
        compute_step(AsmL + cur*8192, BsmL + cur*8192, lane, wm, wn, acc);
        __syncthreads();
        cur = nxt;
    }
    compute_step(AsmL + cur*8192, BsmL + cur*8192, lane, wm, wn, acc);
    __syncthreads();
}

// ---------------------------------------------------------------------------
// Q + KV projections. grid (6,144): col-blocks 0-1 = Q, 2-5 = KV.
// ---------------------------------------------------------------------------
__global__ __launch_bounds__(256, 2)
void qkv_gemm_kernel(const u16* __restrict__ Aq, const u16* __restrict__ As,
                     const u16* __restrict__ Wall,
                     const float* __restrict__ bq, const float* __restrict__ bk,
                     const float* __restrict__ bv,
                     u16* __restrict__ Qbf, u16* __restrict__ KVbf) {
    __shared__ u16 AsmL[2*8192];
    __shared__ u16 BsmL[2*8192];
    int tid = threadIdx.x;
    int lane = tid & 63, wid = tid >> 6;
    int wm = (wid >> 1) * 64, wn = (wid & 1) * 64;
    int bc, br;
    xcd_remap<6, 144>(bc, br);
    int row0 = br * 128;
    bool isQ = (bc < 2);
    int colQ = (isQ ? bc : bc - 2) * 128;
    int wrow0 = isQ ? colQ : 256 + colQ;
    const u16* A = isQ ? Aq : As;
    f32x4 acc[4][4] = {};
    accum_pipe<C_>(A, C_, row0, Wall + (size_t)wrow0 * C_, C_,
                   AsmL, BsmL, tid, lane, wm, wn, acc);
    #pragma unroll
    for (int j = 0; j < 4; ++j) {
        int col = colQ + wn + j*16 + (lane & 15);
        float bb = isQ ? bq[col] : (col < 256 ? bk[col] : bv[col - 256]);
        #pragma unroll
        for (int i = 0; i < 4; ++i) {
            #pragma unroll
            for (int r = 0; r < 4; ++r) {
                int row = row0 + wm + i*16 + (lane >> 4)*4 + r;
                float v = acc[i][j][r] + bb;
                if (isQ) Qbf[(size_t)row*256 + col] = bfbits(v);
                else     KVbf[(size_t)row*512 + col] = bfbits(v);
            }
        }
    }
}

// ---------------------------------------------------------------------------
// Fused gate + output projection + residual (dual accumulator):
// out = query + sigmoid(Xq@Wg^T + bg) * (ctx@Wo^T + bo), f32 out.
// ---------------------------------------------------------------------------
__global__ __launch_bounds__(256, 2)
void final_fused_kernel(const float* __restrict__ query, const u16* __restrict__ Xq,
                        const u16* __restrict__ Wall_g, const float* __restrict__ bg,
                        const u16* __restrict__ ctxb, const u16* __restrict__ Wo_b,
                        const float* __restrict__ bo, float* __restrict__ out) {
    __shared__ u16 AsmL[2*8192];
    __shared__ u16 BsmL[2*8192];
    int tid = threadIdx.x;
    int lane = tid & 63, wid = tid >> 6;
    int wm = (wid >> 1) * 64, wn = (wid & 1) * 64;
    int bc, br;
    xcd_remap<8, 144>(bc, br);
    int row0 = br * 128, col0 = bc * 128;
    f32x4 acc_o[4][4] = {};
    f32x4 acc_g[4][4] = {};
    accum_pipe<INNER_>(ctxb, INNER_, row0, Wo_b + (size_t)col0 * INNER_, INNER_,
                       AsmL, BsmL, tid, lane, wm, wn, acc_o);
    accum_pipe<C_>(Xq, C_, row0, Wall_g + (size_t)col0 * C_, C_,
                   AsmL, BsmL, tid, lane, wm, wn, acc_g);
    #pragma unroll
    for (int i = 0; i < 4; ++i) {
        #pragma unroll
        for (int j = 0; j < 4; ++j) {
            int col = col0 + wn + j*16 + (lane & 15);
            float bgv = bg[col], bov = bo[col];
            #pragma unroll
            for (int r = 0; r < 4; ++r) {
                int row = row0 + wm + i*16 + (lane >> 4)*4 + r;
                size_t idx = (size_t)row * C_ + col;
                float g = 1.f / (1.f + expf(-(acc_g[i][j][r] + bgv)));
                __builtin_nontemporal_store(query[idx] + g * (acc_o[i][j][r] + bov), &out[idx]);
            }
        }
    }
}

// ---------------------------------------------------------------------------
// MFMA attention, K/V from combined KV buffer [M][512]. (validated r3-r10)
// ---------------------------------------------------------------------------
__device__ inline void stage_v_half(const u16* __restrict__ KV, u16* __restrict__ Vt,
                                    int b, int h, int HF, int tid) {
    #pragma unroll
    for (int i = 0; i < 9; ++i) {
        int c = tid + i*256;
        int k = c >> 3;            // 0..287
        int d0 = (c & 7) * 8;
        union { u32x4 v; u16 s[8]; } u;
        u.v = *(const u32x4*)(KV + ((size_t)(b*N_ + HF*288 + k))*512 + 256 + h*HD_ + d0);
        #pragma unroll
        for (int e = 0; e < 8; ++e)
            Vt[(d0 + e)*296 + k] = u.s[e];
    }
}

template<int HF>
__device__ inline void pv_half(const unsigned (&pk)[36][2], f32x4 (&cacc)[4],
                               const u16* __restrict__ Vt, int lane) {
    int s1 = (lane & 15) + ((lane & 16) << 1);
    int s2 = s1 + 16;
    bool hi = (lane & 32) != 0;
    #pragma unroll
    for (int t9 = 0; t9 < 9; ++t9) {
        const int t = HF*9 + t9;
        unsigned A01 = __shfl((int)pk[2*t  ][0], s1, 64);
        unsigned A23 = __shfl((int)pk[2*t  ][1], s1, 64);
        unsigned B01 = __shfl((int)pk[2*t+1][0], s1, 64);
        unsigned B23 = __shfl((int)pk[2*t+1][1], s1, 64);
        unsigned C01 = __shfl((int)pk[2*t  ][0], s2, 64);
        unsigned C23 = __shfl((int)pk[2*t  ][1], s2, 64);
        unsigned D01 = __shfl((int)pk[2*t+1][0], s2, 64);
        unsigned D23 = __shfl((int)pk[2*t+1][1], s2, 64);
        union { unsigned w[4]; bf16x8 v; } bu;
        bu.w[0] = hi ? B01 : A01;
        bu.w[1] = hi ? B23 : A23;
        bu.w[2] = hi ? D01 : C01;
        bu.w[3] = hi ? D23 : C23;
        int colb = 32*t - 288*HF + 8*(lane >> 4);
        #pragma unroll
        for (int dt = 0; dt < 4; ++dt) {
            bf16x8 a = *(const bf16x8*)&Vt[(16*dt + (lane & 15))*296 + colb];
            cacc[dt] = __builtin_amdgcn_mfma_f32_16x16x32_bf16(a, bu.v, cacc[dt], 0, 0, 0);
        }
    }
}

__global__ __launch_bounds__(256, 2)
void attn_mfma_kernel(const u16* __restrict__ Qbf, const u16* __restrict__ KV,
                      const float* __restrict__ mask,
                      float* __restrict__ attn_out, u16* __restrict__ ctxb) {
    __shared__ u16 Vt[64*296];
    __shared__ float Msk[576];
    int tid = threadIdx.x;
    int lane = tid & 63, wid = tid >> 6;
    int qb, bh;
    xcd_remap<9, 128>(qb, bh);
    int b = bh >> 2, h = bh & 3;
    int q0 = qb * 64;
    int g = lane >> 4;
    int qrow = q0 + wid*16 + (lane & 15);

    if (tid < 144) {
        float4 mv = *(const float4*)(mask + b*N_ + tid*4);
        *(float4*)&Msk[tid*4] = make_float4(ALPHA_*mv.x, ALPHA_*mv.y, ALPHA_*mv.z, ALPHA_*mv.w);
    }
    stage_v_half(KV, Vt, b, h, 0, tid);
    __syncthreads();

    const u16* qp = Qbf + ((size_t)(b*N_) + qrow)*INNER_ + h*HD_ + g*8;
    bf16x8 qf0 = *(const bf16x8*)qp;
    bf16x8 qf1 = *(const bf16x8*)(qp + 32);

    f32x4 acc[36];
    #pragma unroll
    for (int T = 0; T < 36; ++T) acc[T] = (f32x4){0.f, 0.f, 0.f, 0.f};

    const u16* kp = KV + ((size_t)(b*N_) + (lane & 15))*512 + h*HD_ + g*8;
    bf16x8 kb[2][2];
    kb[0][0] = *(const bf16x8*)(kp);
    kb[0][1] = *(const bf16x8*)(kp + 32);
    kb[1][0] = *(const bf16x8*)(kp + 16*512);
    kb[1][1] = *(const bf16x8*)(kp + 16*512 + 32);
    #pragma unroll
    for (int T = 0; T < 36; ++T) {
        bf16x8 n0, n1;
        if (T + 2 < 36) {
            n0 = *(const bf16x8*)(kp + (size_t)(T+2)*16*512);
            n1 = *(const bf16x8*)(kp + (size_t)(T+2)*16*512 + 32);
        }
        acc[T] = __builtin_amdgcn_mfma_f32_16x16x32_bf16(kb[T&1][0], qf0, acc[T], 0, 0, 0);
        acc[T] = __builtin_amdgcn_mfma_f32_16x16x32_bf16(kb[T&1][1], qf1, acc[T], 0, 0, 0);
        if (T + 2 < 36) { kb[T&1][0] = n0; kb[T&1][1] = n1; }
    }

    float m = -1e30f;
    #pragma unroll
    for (int T = 0; T < 36; ++T) {
        float4 mk = *(const float4*)&Msk[16*T + 4*g];
        acc[T][0] = acc[T][0]*0.125f + mk.x;
        acc[T][1] = acc[T][1]*0.125f + mk.y;
        acc[T][2] = acc[T][2]*0.125f + mk.z;
        acc[T][3] = acc[T][3]*0.125f + mk.w;
        m = fmaxf(m, fmaxf(fmaxf(acc[T][0], acc[T][1]), fmaxf(acc[T][2], acc[T][3])));
    }
    m = fmaxf(m, __shfl_xor(m, 16, 64));
    m = fmaxf(m, __shfl_xor(m, 32, 64));

    float l = 0.f;
    #pragma unroll
    for (int T = 0; T < 36; ++T) {
        acc[T][0] = expf(acc[T][0] - m);
        acc[T][1] = expf(acc[T][1] - m);
        acc[T][2] = expf(acc[T][2] - m);
        acc[T][3] = expf(acc[T][3] - m);
        l += acc[T][0] + acc[T][1] + acc[T][2] + acc[T][3];
    }
    l += __shfl_xor(l, 16, 64);
    l += __shfl_xor(l, 32, 64);
    float inv = 1.f / l;

    unsigned pk[36][2];
    float* ap = attn_out + ((size_t)bh*N_ + qrow)*N_;
    #pragma unroll
    for (int T = 0; T < 36; ++T) {
        float e0 = acc[T][0]*inv, e1 = acc[T][1]*inv;
        float e2 = acc[T][2]*inv, e3 = acc[T][3]*inv;
        f32x4 ov = {e0, e1, e2, e3};
        __builtin_nontemporal_store(ov, (f32x4*)(ap + 16*T + 4*g));
        pk[T][0] = pack2bf(e0, e1);
        pk[T][1] = pack2bf(e2, e3);
    }

    f32x4 cacc[4] = {};
    pv_half<0>(pk, cacc, Vt, lane);
    __syncthreads();
    stage_v_half(KV, Vt, b, h, 1, tid);
    __syncthreads();
    pv_half<1>(pk, cacc, Vt, lane);

    u16* cp = ctxb + ((size_t)(b*N_) + qrow)*INNER_ + h*HD_ + 4*g;
    #pragma unroll
    for (int dt = 0; dt < 4; ++dt) {
        ushort4 o;
        o.x = bfbits(cacc[dt][0]);
        o.y = bfbits(cacc[dt][1]);
        o.z = bfbits(cacc[dt][2]);
        o.w = bfbits(cacc[dt][3]);
        *(ushort4*)(cp + 16*dt) = o;
    }
}

// ---------------------------------------------------------------------------
extern "C" void kernel_launch(void* const* d_in, const int* in_sizes, int n_in,
                              void* d_out, int out_size, void* d_ws, size_t ws_size,
                              hipStream_t stream) {
    const float* query   = (const float*)d_in[0];
    const float* support = (const float*)d_in[1];
    const float* mask    = (const float*)d_in[2];
    const float* ln_q_w  = (const float*)d_in[3];
    const float* ln_q_b  = (const float*)d_in[4];
    const float* ln_s_w  = (const float*)d_in[5];
    const float* ln_s_b  = (const float*)d_in[6];
    const float* Wq      = (const float*)d_in[7];
    const float* bq      = (const float*)d_in[8];
    const float* Wk      = (const float*)d_in[9];
    const float* bk      = (const float*)d_in[10];
    const float* Wv      = (const float*)d_in[11];
    const float* bv      = (const float*)d_in[12];
    const float* Wo      = (const float*)d_in[13];
    const float* bo      = (const float*)d_in[14];
    const float* Wg      = (const float*)d_in[15];
    const float* bg      = (const float*)d_in[16];

    float* out      = (float*)d_out;
    float* attn_out = out + (size_t)M_ * C_;

    char* w = (char*)d_ws;
    u16* Aq    = (u16*)w;  w += (size_t)M_*C_*2;
    u16* As_   = (u16*)w;  w += (size_t)M_*C_*2;
    u16* Xq    = (u16*)w;  w += (size_t)M_*C_*2;
    u16* Wall  = (u16*)w;  w += (size_t)1792*C_*2;
    u16* Wo_b  = (u16*)w;  w += (size_t)C_*INNER_*2;
    u16* Qbf   = (u16*)w;  w += (size_t)M_*INNER_*2;
    u16* KVbf  = (u16*)w;  w += (size_t)M_*2*INNER_*2;
    u16* ctxb  = (u16*)w;  w += (size_t)M_*INNER_*2;

    // Fused LN for both tensors; query pass also emits raw bf16 (Xq)
    ln_fused2_kernel<<<dim3(M_/4, 2), dim3(256), 0, stream>>>(
        query, support, ln_q_w, ln_q_b, ln_s_w, ln_s_b, Aq, As_, Xq);

    // Weight conversions into combined Wall + Wo_b
    cvt_weights_kernel<<<dim3(1024), dim3(256), 0, stream>>>(
        Wq, Wk, Wv, Wo, Wg, Wall, Wo_b);

    // Q + KV projections (swizzled async 2-phase pipeline)
    qkv_gemm_kernel<<<dim3(6, 144), dim3(256), 0, stream>>>(
        Aq, As_, Wall, bq, bk, bv, Qbf, KVbf);

    // attention
    attn_mfma_kernel<<<dim3(N_/64, B_*H_), dim3(256), 0, stream>>>(
        Qbf, KVbf, mask, attn_out, ctxb);

    // fused gate + output proj + residual
    final_fused_kernel<<<dim3(8, 144), dim3(256), 0, stream>>>(
        query, Xq, Wall + (size_t)768 * C_, bg, ctxb, Wo_b, bo, out);
}